// Round 2
// baseline (3147.080 us; speedup 1.0000x reference)
//
#include <hip/hip_runtime.h>
#include <hip/hip_bf16.h>
#include <cstdint>
#include <cstddef>

// Problem constants
#define Bsz 8192
#define Hdim 2048
#define Kdim 4096   // EFF
#define Nall 4096   // 2*H in Wt: rows 0..2047 cand, 2048..4095 gate

// GEMM tiling
#define BM 128
#define BN 128      // cand cols per block; gate cols fused in same block
#define BK 32

typedef __attribute__((ext_vector_type(8))) short short8;   // 8 bf16
typedef __attribute__((ext_vector_type(4))) short short4v;  // 4 bf16 (8B)
typedef __attribute__((ext_vector_type(4))) float floatx4;

// fp32 -> bf16 bits, round-to-nearest-even
__device__ __forceinline__ short f2bf(float f) {
    unsigned u = __float_as_uint(f);
    unsigned r = (u + 0x7fffu + ((u >> 16) & 1u)) >> 16;
    return (short)(r & 0xffffu);
}

__device__ __forceinline__ float fast_tanh(float x) {
    // 1 - 2/(e^{2x}+1); saturates correctly for large |x|
    float e = __expf(2.f * x);
    return 1.f - 2.f / (e + 1.f);
}
__device__ __forceinline__ float fast_sigmoid(float x) {
    return 1.f / (1.f + __expf(-x));
}

// async global->LDS, 16B/lane; LDS dest = wave-uniform base + lane*16
__device__ __forceinline__ void g2l16(const void* g, void* l) {
    __builtin_amdgcn_global_load_lds(
        (const __attribute__((address_space(1))) unsigned int*)g,
        (__attribute__((address_space(3))) unsigned int*)l,
        16, 0, 0);
}

// ---------------------------------------------------------------------------
// Kernel 1: combined weight build + transpose.
// Wt[n][k] (bf16) = n<2048 ? Wc[k][n] + (k>=2048)*Uc[k-2048][n]
//                          : Wg[k][n-2048] + (k>=2048)*Ug[k-2048][n-2048]
// 32x32 LDS-tiled; vectorized 8B stores (short4).
// ---------------------------------------------------------------------------
__global__ __launch_bounds__(256) void build_wt(
    const float* __restrict__ Wc, const float* __restrict__ Uc,
    const float* __restrict__ Wg, const float* __restrict__ Ug,
    short* __restrict__ Wt)
{
    __shared__ float tile[32][33];
    const int nt = blockIdx.x * 32;   // n tile base
    const int kt = blockIdx.y * 32;   // k tile base
    const int tx = threadIdx.x & 31;
    const int ty = threadIdx.x >> 5;  // 0..7

    const bool isGate = (nt >= Hdim);
    const float* W = isGate ? Wg : Wc;
    const float* U = isGate ? Ug : Uc;
    const int ncol = isGate ? (nt - Hdim) : nt;

#pragma unroll
    for (int r = 0; r < 32; r += 8) {
        int k = kt + ty + r;
        float v = W[(size_t)k * Hdim + ncol + tx];
        if (k >= Hdim) v += U[(size_t)(k - Hdim) * Hdim + ncol + tx];
        tile[ty + r][tx] = v;
    }
    __syncthreads();
    // store: thread -> (n row, 4-wide k group); 8B vector store
    const int nrow = threadIdx.x >> 3;   // 0..31
    const int kg   = threadIdx.x & 7;    // 0..7
    short4v o;
#pragma unroll
    for (int i = 0; i < 4; ++i) o[i] = f2bf(tile[kg * 4 + i][nrow]);
    *(short4v*)&Wt[(size_t)(nt + nrow) * Kdim + kt + kg * 4] = o;
}

// ---------------------------------------------------------------------------
// Kernel 2: Acat[b][k] (bf16) = k<2048 ? x_t[b][k] : state[b][k-2048]
// ---------------------------------------------------------------------------
__global__ __launch_bounds__(256) void build_acat(
    const float* __restrict__ x, const float* __restrict__ st,
    short* __restrict__ A)
{
    int idx = blockIdx.x * 256 + threadIdx.x;
    int row = idx >> 9;                  // 512 groups of 8 per row
    int c = (idx & 511) * 8;             // wave-uniform branch
    const float* src = (c < Hdim) ? (x + (size_t)row * Hdim + c)
                                  : (st + (size_t)row * Hdim + (c - Hdim));
    float4 v0 = ((const float4*)src)[0];
    float4 v1 = ((const float4*)src)[1];
    short8 o;
    o[0] = f2bf(v0.x); o[1] = f2bf(v0.y); o[2] = f2bf(v0.z); o[3] = f2bf(v0.w);
    o[4] = f2bf(v1.x); o[5] = f2bf(v1.y); o[6] = f2bf(v1.z); o[7] = f2bf(v1.w);
    *(short8*)(A + (size_t)row * Kdim + c) = o;
}

// ---------------------------------------------------------------------------
// Kernel 3: fused GEMM. Block computes 128(m) x 128(n) of BOTH cand and gate
// preacts (B rows n and 2048+n), 32 MFMA/wave per K-iter, then applies
// tanh/sigmoid/alpha-blend with state in-register and writes h [B][2048] fp32.
// LDS K-chunk XOR swizzle ((row>>1)&3) kills the 4-way b128 bank conflicts.
// ---------------------------------------------------------------------------
__global__ void gemm_fused(
    const short* __restrict__ A,    // [8192][4096] bf16
    const short* __restrict__ Bt,   // [4096][4096] bf16 (cand|gate rows)
    const float* __restrict__ st,   // [8192][2048]
    const float* __restrict__ bc, const float* __restrict__ bg,
    const float* __restrict__ lstep,
    float* __restrict__ Hout)       // [8192][2048]
{
    __shared__ __attribute__((aligned(16))) short sA [BM * BK];
    __shared__ __attribute__((aligned(16))) short sBc[BN * BK];
    __shared__ __attribute__((aligned(16))) short sBg[BN * BK];

    const int tid  = threadIdx.x;
    const int lane = tid & 63;
    const int wave = tid >> 6;
    const int wm = wave >> 1;   // 0..1
    const int wn = wave & 1;

    const int m0 = blockIdx.y * BM;
    const int n0 = blockIdx.x * BN;
    const int K = Kdim;

    floatx4 accc[4][4], accg[4][4];
#pragma unroll
    for (int i = 0; i < 4; ++i)
#pragma unroll
        for (int j = 0; j < 4; ++j) {
            floatx4 z = {0.f, 0.f, 0.f, 0.f};
            accc[i][j] = z; accg[i][j] = z;
        }

    // staging: LDS chunk c=tid (+256) is row c>>2, slot c&3 (16B chunks).
    // Source k-chunk = slot ^ ((row>>1)&3)  (same swizzle for row and row+64).
    const int r0 = tid >> 2;
    const int c0 = ((tid & 3) ^ ((r0 >> 1) & 3)) * 8;
    const short* Ag0 = A  + (size_t)(m0 + r0)        * K + c0;
    const short* Ag1 = A  + (size_t)(m0 + 64 + r0)   * K + c0;
    const short* Bc0 = Bt + (size_t)(n0 + r0)        * K + c0;
    const short* Bc1 = Bt + (size_t)(n0 + 64 + r0)   * K + c0;
    const short* Bg0 = Bt + (size_t)(Hdim + n0 + r0)      * K + c0;
    const short* Bg1 = Bt + (size_t)(Hdim + n0 + 64 + r0) * K + c0;

    // wave-uniform LDS bases (chunk tid = wave*64+lane -> byte wave*1024+lane*16)
    short* dA0  = sA  + wave * 512;          short* dA1  = sA  + 2048 + wave * 512;
    short* dBc0 = sBc + wave * 512;          short* dBc1 = sBc + 2048 + wave * 512;
    short* dBg0 = sBg + wave * 512;          short* dBg1 = sBg + 2048 + wave * 512;

    // fragment reads: row fr, want global k-chunk j -> LDS slot j ^ ((fr>>1)&3)
    const int fr = lane & 15;
    const int j4 = lane >> 4;                 // k-chunk 0..3
    const int rslot = (j4 ^ ((fr >> 1) & 3)) * 8;
    const short* sAf  = sA  + (wm * 64 + fr) * BK + rslot;
    const short* sBcf = sBc + (wn * 64 + fr) * BK + rslot;
    const short* sBgf = sBg + (wn * 64 + fr) * BK + rslot;

    for (int k0 = 0; k0 < K; k0 += BK) {
        __syncthreads();
        g2l16(Ag0, dA0);  g2l16(Ag1, dA1);
        g2l16(Bc0, dBc0); g2l16(Bc1, dBc1);
        g2l16(Bg0, dBg0); g2l16(Bg1, dBg1);
        Ag0 += BK; Ag1 += BK; Bc0 += BK; Bc1 += BK; Bg0 += BK; Bg1 += BK;
        __syncthreads();

        short8 a[4], bcf[4], bgf[4];
#pragma unroll
        for (int i = 0; i < 4; ++i) {
            a[i]   = *(const short8*)(sAf  + i * 16 * BK);
            bcf[i] = *(const short8*)(sBcf + i * 16 * BK);
            bgf[i] = *(const short8*)(sBgf + i * 16 * BK);
        }
#pragma unroll
        for (int i = 0; i < 4; ++i)
#pragma unroll
            for (int j = 0; j < 4; ++j) {
                accc[i][j] = __builtin_amdgcn_mfma_f32_16x16x32_bf16(
                    a[i], bcf[j], accc[i][j], 0, 0, 0);
                accg[i][j] = __builtin_amdgcn_mfma_f32_16x16x32_bf16(
                    a[i], bgf[j], accg[i][j], 0, 0, 0);
            }
    }

    // epilogue: C/D layout col=lane&15, row=(lane>>4)*4+reg  [m89/m91]
    const int cn = lane & 15;
    const int cr = (lane >> 4) * 4;
    float bcv[4], bgv[4], alv[4];
#pragma unroll
    for (int j = 0; j < 4; ++j) {
        int col = n0 + wn * 64 + j * 16 + cn;
        bcv[j] = bc[col];
        bgv[j] = bg[col];
        alv[j] = __expf(-__expf(-lstep[col]));
    }
#pragma unroll
    for (int i = 0; i < 4; ++i) {
        int rowb = m0 + wm * 64 + i * 16 + cr;
#pragma unroll
        for (int r = 0; r < 4; ++r) {
            int row = rowb + r;
            const float* sp = st + (size_t)row * Hdim;
            float* hp = Hout + (size_t)row * Hdim;
#pragma unroll
            for (int j = 0; j < 4; ++j) {
                int col = n0 + wn * 64 + j * 16 + cn;
                float cand = fast_tanh(accc[i][j][r] + bcv[j]);
                float gate = fast_sigmoid(accg[i][j][r] + bgv[j]);
                float al = alv[j];
                hp[col] = al * sp[col] + (1.f - al) * gate * cand;
            }
        }
    }
}

// ---------------------------------------------------------------------------
// Kernel 4: LayerNorm over h rows. One block per batch row.
// ---------------------------------------------------------------------------
__global__ __launch_bounds__(256) void ln_k(
    const float* __restrict__ h, const float* __restrict__ gam,
    const float* __restrict__ bet, float* __restrict__ out)
{
    const int b = blockIdx.x;
    const int t = threadIdx.x;
    const int n0 = t * 8;
    const float* hp = h + (size_t)b * Hdim + n0;

    float4 v0 = ((const float4*)hp)[0];
    float4 v1 = ((const float4*)hp)[1];
    float hv[8] = {v0.x, v0.y, v0.z, v0.w, v1.x, v1.y, v1.z, v1.w};
    float sum = 0.f, ss = 0.f;
#pragma unroll
    for (int i = 0; i < 8; ++i) { sum += hv[i]; ss += hv[i] * hv[i]; }

#pragma unroll
    for (int off = 32; off > 0; off >>= 1) {
        sum += __shfl_down(sum, off);
        ss  += __shfl_down(ss, off);
    }
    __shared__ float red[2][4];
    if ((t & 63) == 0) { red[0][t >> 6] = sum; red[1][t >> 6] = ss; }
    __syncthreads();
    sum = red[0][0] + red[0][1] + red[0][2] + red[0][3];
    ss  = red[1][0] + red[1][1] + red[1][2] + red[1][3];

    const float inv = 1.f / (float)Hdim;
    float mu = sum * inv;
    float var = ss * inv - mu * mu;
    float rs = rsqrtf(var + 1e-5f);

    float* op = out + (size_t)b * Hdim + n0;
#pragma unroll
    for (int i = 0; i < 8; ++i) {
        int n = n0 + i;
        op[i] = (hv[i] - mu) * rs * gam[n] + bet[n];
    }
}

// ---------------------------------------------------------------------------
extern "C" void kernel_launch(void* const* d_in, const int* in_sizes, int n_in,
                              void* d_out, int out_size, void* d_ws, size_t ws_size,
                              hipStream_t stream)
{
    const float* x_t   = (const float*)d_in[0];
    const float* state = (const float*)d_in[1];
    const float* Wc    = (const float*)d_in[2];
    const float* Uc    = (const float*)d_in[3];
    const float* bc    = (const float*)d_in[4];
    const float* Wg    = (const float*)d_in[5];
    const float* Ug    = (const float*)d_in[6];
    const float* bg    = (const float*)d_in[7];
    const float* lstep = (const float*)d_in[8];
    const float* gam   = (const float*)d_in[9];
    const float* bet   = (const float*)d_in[10];
    float* out = (float*)d_out;

    // workspace: Wt (32MB) | Acat (64MB) | h (64MB fp32) = 160MB
    char* ws = (char*)d_ws;
    short* Wt   = (short*)ws;
    short* Acat = (short*)(ws + (size_t)32 * 1024 * 1024);
    float* h    = (float*)(ws + (size_t)96 * 1024 * 1024);

    build_wt<<<dim3(Nall / 32, Kdim / 32), 256, 0, stream>>>(Wc, Uc, Wg, Ug, Wt);
    build_acat<<<(Bsz * (Kdim / 8)) / 256, 256, 0, stream>>>(x_t, state, Acat);
    gemm_fused<<<dim3(Hdim / BN, Bsz / BM), 256, 0, stream>>>(
        Acat, Wt, state, bc, bg, lstep, h);
    ln_k<<<Bsz, 256, 0, stream>>>(h, gam, bet, out);
}

// Round 3
// 581.706 us; speedup vs baseline: 5.4101x; 5.4101x over previous
//
#include <hip/hip_runtime.h>
#include <hip/hip_bf16.h>
#include <cstdint>
#include <cstddef>

// Problem constants
#define Bsz 8192
#define Hdim 2048
#define Kdim 4096   // EFF
#define Nall 4096   // 2*H in Wt: rows 0..2047 cand, 2048..4095 gate

// GEMM tiling: block = 128(m) x 64(n), but computes BOTH cand and gate
// preacts for those 64 n-cols => effective 128x128 of the stacked GEMM.
#define BM 128
#define BN 64
#define BK 32

typedef __attribute__((ext_vector_type(8))) short short8;   // 8 bf16
typedef __attribute__((ext_vector_type(4))) short short4v;  // 4 bf16 (8B)
typedef __attribute__((ext_vector_type(4))) float floatx4;

// fp32 -> bf16 bits, round-to-nearest-even
__device__ __forceinline__ short f2bf(float f) {
    unsigned u = __float_as_uint(f);
    unsigned r = (u + 0x7fffu + ((u >> 16) & 1u)) >> 16;
    return (short)(r & 0xffffu);
}

__device__ __forceinline__ float fast_tanh(float x) {
    float e = __expf(2.f * x);
    return 1.f - 2.f / (e + 1.f);
}
__device__ __forceinline__ float fast_sigmoid(float x) {
    return 1.f / (1.f + __expf(-x));
}

// async global->LDS, 16B/lane; LDS dest = wave-uniform base + lane*16
__device__ __forceinline__ void g2l16(const void* g, void* l) {
    __builtin_amdgcn_global_load_lds(
        (const __attribute__((address_space(1))) unsigned int*)g,
        (__attribute__((address_space(3))) unsigned int*)l,
        16, 0, 0);
}

// ---------------------------------------------------------------------------
// Kernel 1: combined weight build + transpose.
// Wt[n][k] (bf16) = n<2048 ? Wc[k][n] + (k>=2048)*Uc[k-2048][n]
//                          : Wg[k][n-2048] + (k>=2048)*Ug[k-2048][n-2048]
// ---------------------------------------------------------------------------
__global__ __launch_bounds__(256) void build_wt(
    const float* __restrict__ Wc, const float* __restrict__ Uc,
    const float* __restrict__ Wg, const float* __restrict__ Ug,
    short* __restrict__ Wt)
{
    __shared__ float tile[32][33];
    const int nt = blockIdx.x * 32;   // n tile base
    const int kt = blockIdx.y * 32;   // k tile base
    const int tx = threadIdx.x & 31;
    const int ty = threadIdx.x >> 5;  // 0..7

    const bool isGate = (nt >= Hdim);
    const float* W = isGate ? Wg : Wc;
    const float* U = isGate ? Ug : Uc;
    const int ncol = isGate ? (nt - Hdim) : nt;

#pragma unroll
    for (int r = 0; r < 32; r += 8) {
        int k = kt + ty + r;
        float v = W[(size_t)k * Hdim + ncol + tx];
        if (k >= Hdim) v += U[(size_t)(k - Hdim) * Hdim + ncol + tx];
        tile[ty + r][tx] = v;
    }
    __syncthreads();
    const int nrow = threadIdx.x >> 3;   // 0..31
    const int kg   = threadIdx.x & 7;    // 0..7
    short4v o;
#pragma unroll
    for (int i = 0; i < 4; ++i) o[i] = f2bf(tile[kg * 4 + i][nrow]);
    *(short4v*)&Wt[(size_t)(nt + nrow) * Kdim + kt + kg * 4] = o;
}

// ---------------------------------------------------------------------------
// Kernel 2: Acat[b][k] (bf16) = k<2048 ? x_t[b][k] : state[b][k-2048]
// ---------------------------------------------------------------------------
__global__ __launch_bounds__(256) void build_acat(
    const float* __restrict__ x, const float* __restrict__ st,
    short* __restrict__ A)
{
    int idx = blockIdx.x * 256 + threadIdx.x;
    int row = idx >> 9;                  // 512 groups of 8 per row
    int c = (idx & 511) * 8;             // wave-uniform branch
    const float* src = (c < Hdim) ? (x + (size_t)row * Hdim + c)
                                  : (st + (size_t)row * Hdim + (c - Hdim));
    float4 v0 = ((const float4*)src)[0];
    float4 v1 = ((const float4*)src)[1];
    short8 o;
    o[0] = f2bf(v0.x); o[1] = f2bf(v0.y); o[2] = f2bf(v0.z); o[3] = f2bf(v0.w);
    o[4] = f2bf(v1.x); o[5] = f2bf(v1.y); o[6] = f2bf(v1.z); o[7] = f2bf(v1.w);
    *(short8*)(A + (size_t)row * Kdim + c) = o;
}

// ---------------------------------------------------------------------------
// Kernel 3: fused GEMM. Block: 128(m) x 64(n) of cand AND gate preacts.
// Per wave: accc[4][2] + accg[4][2] = 64 acc regs (same budget as R1's
// proven no-spill kernel). 16 MFMA/wave/K-iter. Gating epilogue in-register,
// writes h [8192][2048] fp32. XOR K-chunk swizzle keeps conflicts at 0.
// ---------------------------------------------------------------------------
__global__ __launch_bounds__(256, 2) void gemm_fused(
    const short* __restrict__ A,    // [8192][4096] bf16
    const short* __restrict__ Bt,   // [4096][4096] bf16 (cand|gate rows)
    const float* __restrict__ st,   // [8192][2048]
    const float* __restrict__ bc, const float* __restrict__ bg,
    const float* __restrict__ lstep,
    float* __restrict__ Hout)       // [8192][2048]
{
    __shared__ __attribute__((aligned(16))) short sA [BM * BK]; // 8 KB
    __shared__ __attribute__((aligned(16))) short sBc[BN * BK]; // 4 KB
    __shared__ __attribute__((aligned(16))) short sBg[BN * BK]; // 4 KB

    const int tid  = threadIdx.x;
    const int lane = tid & 63;
    const int wave = tid >> 6;
    const int wm = wave >> 1;   // 0..1 (m half)
    const int wn = wave & 1;    // 0..1 (n half of 64)

    const int m0 = blockIdx.y * BM;
    const int n0 = blockIdx.x * BN;
    const int K = Kdim;

    floatx4 accc[4][2], accg[4][2];
#pragma unroll
    for (int i = 0; i < 4; ++i)
#pragma unroll
        for (int j = 0; j < 2; ++j) {
            floatx4 z = {0.f, 0.f, 0.f, 0.f};
            accc[i][j] = z; accg[i][j] = z;
        }

    // staging addresses. Chunk c: row c>>2, LDS slot c&3; global source
    // k-chunk = slot ^ ((row>>1)&3)  (row and row+64 give same swizzle).
    const int r0 = tid >> 2;              // 0..63
    const int c0 = ((tid & 3) ^ ((r0 >> 1) & 3)) * 8;
    const short* Ag0 = A  + (size_t)(m0 + r0)        * K + c0;  // A rows 0..63
    const short* Ag1 = A  + (size_t)(m0 + 64 + r0)   * K + c0;  // A rows 64..127
    const short* Bc0 = Bt + (size_t)(n0 + r0)        * K + c0;  // cand rows 0..63
    const short* Bg0 = Bt + (size_t)(Hdim + n0 + r0) * K + c0;  // gate rows 0..63

    // wave-uniform LDS dests (chunk tid -> byte wave*1024 + lane*16)
    short* dA0 = sA  + wave * 512;
    short* dA1 = sA  + 2048 + wave * 512;
    short* dBc = sBc + wave * 512;
    short* dBg = sBg + wave * 512;

    // fragment read addresses: row fr, k-chunk j4 -> LDS slot j4^((fr>>1)&3)
    const int fr = lane & 15;
    const int j4 = lane >> 4;
    const int rslot = (j4 ^ ((fr >> 1) & 3)) * 8;
    const short* sAf  = sA  + (wm * 64 + fr) * BK + rslot;
    const short* sBcf = sBc + (wn * 32 + fr) * BK + rslot;
    const short* sBgf = sBg + (wn * 32 + fr) * BK + rslot;

    for (int k0 = 0; k0 < K; k0 += BK) {
        __syncthreads();
        g2l16(Ag0, dA0); g2l16(Ag1, dA1);
        g2l16(Bc0, dBc); g2l16(Bg0, dBg);
        Ag0 += BK; Ag1 += BK; Bc0 += BK; Bg0 += BK;
        __syncthreads();

        short8 a[4], bcf[2], bgf[2];
#pragma unroll
        for (int i = 0; i < 4; ++i) a[i] = *(const short8*)(sAf + i * 16 * BK);
#pragma unroll
        for (int j = 0; j < 2; ++j) {
            bcf[j] = *(const short8*)(sBcf + j * 16 * BK);
            bgf[j] = *(const short8*)(sBgf + j * 16 * BK);
        }
#pragma unroll
        for (int i = 0; i < 4; ++i)
#pragma unroll
            for (int j = 0; j < 2; ++j) {
                accc[i][j] = __builtin_amdgcn_mfma_f32_16x16x32_bf16(
                    a[i], bcf[j], accc[i][j], 0, 0, 0);
                accg[i][j] = __builtin_amdgcn_mfma_f32_16x16x32_bf16(
                    a[i], bgf[j], accg[i][j], 0, 0, 0);
            }
    }

    // epilogue: C/D layout col=lane&15, row=(lane>>4)*4+reg  [m89/m91]
    const int cn = lane & 15;
    const int cr = (lane >> 4) * 4;
    float bcv[2], bgv[2], alv[2];
#pragma unroll
    for (int j = 0; j < 2; ++j) {
        int col = n0 + wn * 32 + j * 16 + cn;
        bcv[j] = bc[col];
        bgv[j] = bg[col];
        alv[j] = __expf(-__expf(-lstep[col]));
    }
#pragma unroll
    for (int i = 0; i < 4; ++i) {
        int rowb = m0 + wm * 64 + i * 16 + cr;
#pragma unroll
        for (int r = 0; r < 4; ++r) {
            int row = rowb + r;
            const float* sp = st + (size_t)row * Hdim;
            float* hp = Hout + (size_t)row * Hdim;
#pragma unroll
            for (int j = 0; j < 2; ++j) {
                int col = n0 + wn * 32 + j * 16 + cn;
                float cand = fast_tanh(accc[i][j][r] + bcv[j]);
                float gate = fast_sigmoid(accg[i][j][r] + bgv[j]);
                float al = alv[j];
                hp[col] = al * sp[col] + (1.f - al) * gate * cand;
            }
        }
    }
}

// ---------------------------------------------------------------------------
// Kernel 4: LayerNorm over h rows. One block per batch row.
// ---------------------------------------------------------------------------
__global__ __launch_bounds__(256) void ln_k(
    const float* __restrict__ h, const float* __restrict__ gam,
    const float* __restrict__ bet, float* __restrict__ out)
{
    const int b = blockIdx.x;
    const int t = threadIdx.x;
    const int n0 = t * 8;
    const float* hp = h + (size_t)b * Hdim + n0;

    float4 v0 = ((const float4*)hp)[0];
    float4 v1 = ((const float4*)hp)[1];
    float hv[8] = {v0.x, v0.y, v0.z, v0.w, v1.x, v1.y, v1.z, v1.w};
    float sum = 0.f, ss = 0.f;
#pragma unroll
    for (int i = 0; i < 8; ++i) { sum += hv[i]; ss += hv[i] * hv[i]; }

#pragma unroll
    for (int off = 32; off > 0; off >>= 1) {
        sum += __shfl_down(sum, off);
        ss  += __shfl_down(ss, off);
    }
    __shared__ float red[2][4];
    if ((t & 63) == 0) { red[0][t >> 6] = sum; red[1][t >> 6] = ss; }
    __syncthreads();
    sum = red[0][0] + red[0][1] + red[0][2] + red[0][3];
    ss  = red[1][0] + red[1][1] + red[1][2] + red[1][3];

    const float inv = 1.f / (float)Hdim;
    float mu = sum * inv;
    float var = ss * inv - mu * mu;
    float rs = rsqrtf(var + 1e-5f);

    float* op = out + (size_t)b * Hdim + n0;
#pragma unroll
    for (int i = 0; i < 8; ++i) {
        int n = n0 + i;
        op[i] = (hv[i] - mu) * rs * gam[n] + bet[n];
    }
}

// ---------------------------------------------------------------------------
extern "C" void kernel_launch(void* const* d_in, const int* in_sizes, int n_in,
                              void* d_out, int out_size, void* d_ws, size_t ws_size,
                              hipStream_t stream)
{
    const float* x_t   = (const float*)d_in[0];
    const float* state = (const float*)d_in[1];
    const float* Wc    = (const float*)d_in[2];
    const float* Uc    = (const float*)d_in[3];
    const float* bc    = (const float*)d_in[4];
    const float* Wg    = (const float*)d_in[5];
    const float* Ug    = (const float*)d_in[6];
    const float* bg    = (const float*)d_in[7];
    const float* lstep = (const float*)d_in[8];
    const float* gam   = (const float*)d_in[9];
    const float* bet   = (const float*)d_in[10];
    float* out = (float*)d_out;

    // workspace: Wt (32MB) | Acat (64MB) | h (64MB fp32) = 160MB
    char* ws = (char*)d_ws;
    short* Wt   = (short*)ws;
    short* Acat = (short*)(ws + (size_t)32 * 1024 * 1024);
    float* h    = (float*)(ws + (size_t)96 * 1024 * 1024);

    build_wt<<<dim3(Nall / 32, Kdim / 32), 256, 0, stream>>>(Wc, Uc, Wg, Ug, Wt);
    build_acat<<<(Bsz * (Kdim / 8)) / 256, 256, 0, stream>>>(x_t, state, Acat);
    gemm_fused<<<dim3(Hdim / BN, Bsz / BM), 256, 0, stream>>>(
        Acat, Wt, state, bc, bg, lstep, h);
    ln_k<<<Bsz, 256, 0, stream>>>(h, gam, bet, out);
}